// Round 12
// baseline (2801.167 us; speedup 1.0000x reference)
//
#include <hip/hip_runtime.h>
#include <hip/hip_bf16.h>

typedef __bf16  bf16x8  __attribute__((ext_vector_type(8)));
typedef short   short8_t __attribute__((ext_vector_type(8)));
typedef float   float4_t __attribute__((ext_vector_type(4)));

#define MFMA(a, b, c) __builtin_amdgcn_mfma_f32_16x16x32_bf16((a), (b), (c), 0, 0, 0)

#define LOG2E      1.4426950408889634f
#define TWO_LOG2E  2.8853900817779268f

__device__ __forceinline__ unsigned short f2bf(float f) {
  return __builtin_bit_cast(unsigned short, static_cast<__bf16>(f));  // HW cvt, RTE
}
// x pre-scaled by LOG2E
__device__ __forceinline__ float sig2(float x) {
  return __builtin_amdgcn_rcpf(1.f + __builtin_amdgcn_exp2f(-x));
}

// 256 blocks x 512 threads (8 waves), 32 rows/block, TWO 16-row streams
// phase-shifted one region apart; trans equalized ~40/region via deferred
// act1 (gates ride MFMA C-regs across one barrier); c-state in the
// 2*log2e-scaled domain. MFMA-FIRST region ordering: within each region all
// MFMAs (incl. PROJ's) issue before the ACT4 trans burst, so the matrix pipe
// drains under VALU. Plain __syncthreads (asm lgkm-barrier convicted R5/R10).
// Per step, 4 barriers:
//   R1: cell0h(s0,t) ; projMFMA(s0) [w<2] ; act1(s1,t-1)->h1f1 ; projFIN(s0)
//   R2: x-part(s0) ; cell0h(s1,t) ; projMFMA(s1) [w=2,3] ; act0(s0)->h0f0 ; projFIN(s1)
//   R3: stores x0(t) ; cell1(s0)->am0 ; x-part(s1) ; act0(s1)->h0f1
//   R4: stores x1(t) ; cell1(s1)->am1 ; act1(s0,am0)->h1f0
__global__ __launch_bounds__(512, 2) void lstm_roll(
    const float* __restrict__ x0,  const float* __restrict__ W0,
    const float* __restrict__ b0v, const float* __restrict__ W1,
    const float* __restrict__ b1v, const float* __restrict__ Wout,
    const float* __restrict__ bout, const float* __restrict__ dts,
    const int* __restrict__ nsp,   float* __restrict__ out)
{
  __shared__ __align__(16) unsigned short w0h[8 * 4 * 4 * 512];  // 128 KiB W0 h-part B-frags [w][g][kt]
  __shared__ __align__(16) unsigned short woutF[2 * 4 * 512];    //   8 KiB Wout B-frags (dts*DT folded)
  __shared__ __align__(16) unsigned short h0f0[4 * 512];         //   4 KiB h0 A-frags, stream0
  __shared__ __align__(16) unsigned short h0f1[4 * 512];         //   4 KiB h0 A-frags, stream1
  __shared__ __align__(16) unsigned short h1f0[4 * 512];         //   4 KiB h1 A-frags, stream0
  __shared__ __align__(16) unsigned short h1f1[4 * 512];         //   4 KiB h1 A-frags, stream1
  __shared__ __align__(16) unsigned short xf0[512];              //   1 KiB x A-frag, stream0
  __shared__ __align__(16) unsigned short xf1[512];              //   1 KiB x A-frag, stream1

  const int tid = threadIdx.x;
  const int w   = tid >> 6;
  const int l   = tid & 63;
  const int lm  = l & 15;
  const int lh  = l >> 4;
  const int T   = nsp[0];
  const long rowStride = (long)(T + 1) * 32;
  const long bbase = (long)blockIdx.x * 32;

  // ---------------- weight gather / packing (once) ----------------
  bf16x8 w0x[4];       // W0 x-part B-frags (K=32)
  bf16x8 w1f[4][8];    // W1 B-frags (K=256; kt 0..3 h0-part, 4..7 h1-part)
  #pragma unroll
  for (int g = 0; g < 4; ++g) {
    const float sc = (g == 2) ? TWO_LOG2E : LOG2E;
    const int col = g * 128 + w * 16 + lm;
    {
      short8_t t8;
      #pragma unroll
      for (int e = 0; e < 8; ++e) t8[e] = (short)f2bf(sc * W0[(lh * 8 + e) * 512 + col]);
      w0x[g] = __builtin_bit_cast(bf16x8, t8);
    }
    #pragma unroll
    for (int kt = 0; kt < 8; ++kt) {
      short8_t t8;
      #pragma unroll
      for (int e = 0; e < 8; ++e) t8[e] = (short)f2bf(sc * W1[(kt * 32 + lh * 8 + e) * 512 + col]);
      w1f[g][kt] = __builtin_bit_cast(bf16x8, t8);
    }
    #pragma unroll
    for (int kt = 0; kt < 4; ++kt) {
      const int base = (((w * 4 + g) * 4) + kt) * 512 + l * 8;
      #pragma unroll
      for (int e = 0; e < 8; ++e)
        w0h[base + e] = f2bf(sc * W0[(32 + kt * 32 + lh * 8 + e) * 512 + col]);
    }
  }
  { // Wout B-frags with dts*DT folded in
    const int n = w & 1, kt = w >> 1;
    if (kt < 4) {
      const float csc = dts[n * 16 + lm] * 0.01f;
      const int base = (n * 4 + kt) * 512 + l * 8;
      #pragma unroll
      for (int e = 0; e < 8; ++e)
        woutF[base + e] = f2bf(csc * Wout[(kt * 32 + lh * 8 + e) * 32 + (n * 16 + lm)]);
    }
  }
  float b0r[4], b1r[4];
  #pragma unroll
  for (int g = 0; g < 4; ++g) {
    const float sc = (g == 2) ? TWO_LOG2E : LOG2E;
    b0r[g] = sc * b0v[g * 128 + w * 16 + lm];
    b1r[g] = sc * b1v[g * 128 + w * 16 + lm];
  }

  // proj/store mapping: waves 0,1 -> stream0 (n_c = w&1); waves 2,3 -> stream1
  const int S_w = (w >> 1) & 1;
  const int n_c = w & 1;
  float boutr = 0.f, xr[4] = {0.f, 0.f, 0.f, 0.f};
  long obase0 = 0;
  int  xfb = 0;
  if (w < 4) {
    boutr = bout[n_c * 16 + lm] * dts[n_c * 16 + lm] * 0.01f;
    const int kin = n_c * 16 + lm;
    xfb = (lh * 4 + 16 * (kin >> 3)) * 8 + (kin & 7);
    obase0 = (bbase + S_w * 16 + lh * 4) * rowStride + (n_c * 16 + lm);
    unsigned short* xfS = S_w ? xf1 : xf0;
    #pragma unroll
    for (int r = 0; r < 4; ++r) {
      xr[r] = x0[(bbase + S_w * 16 + lh * 4 + r) * 32 + n_c * 16 + lm];
      out[obase0 + r * rowStride] = xr[r];   // trajectory t = 0
      xfS[xfb + r * 8] = f2bf(xr[r]);        // seed xf(0)
    }
  }
  for (int i = tid; i < 4 * 512; i += 512) {
    h0f0[i] = 0; h0f1[i] = 0; h1f0[i] = 0; h1f1[i] = 0;
  }

  // h-write scatter base (per-stream fragment layout; kt = w>>1)
  const int hwb = (w >> 1) * 512 +
                  (lh * 4 + 16 * (2 * (w & 1) + ((lm >> 3) & 1))) * 8 + (lm & 7);

  // c-states live in the 2*log2e-scaled domain
  float4_t c0s0 = {0.f,0.f,0.f,0.f}, c0s1 = {0.f,0.f,0.f,0.f};
  float4_t c1s0 = {0.f,0.f,0.f,0.f}, c1s1 = {0.f,0.f,0.f,0.f};

#define INIT4(ACC, B) \
    _Pragma("unroll") \
    for (int g = 0; g < 4; ++g) (ACC)[g] = (float4_t){(B)[g], (B)[g], (B)[g], (B)[g]};

#define CELL0H(HSRC, ACC) \
    _Pragma("unroll") \
    for (int kt = 0; kt < 4; ++kt) { \
      const bf16x8 a = *(const bf16x8*)&(HSRC)[kt * 512 + l * 8]; \
      _Pragma("unroll") \
      for (int g = 0; g < 4; ++g) { \
        const bf16x8 bw = *(const bf16x8*)&w0h[(((w * 4 + g) * 4) + kt) * 512 + l * 8]; \
        (ACC)[g] = MFMA(a, bw, (ACC)[g]); \
      } \
    }

#define XPART(XSRC, ACC) { \
    const bf16x8 ax = *(const bf16x8*)&(XSRC)[l * 8]; \
    _Pragma("unroll") \
    for (int g = 0; g < 4; ++g) (ACC)[g] = MFMA(ax, w0x[g], (ACC)[g]); \
  }

#define CELL1A(H0SRC, AM) \
    _Pragma("unroll") \
    for (int kt = 0; kt < 4; ++kt) { \
      const bf16x8 a = *(const bf16x8*)&(H0SRC)[kt * 512 + l * 8]; \
      _Pragma("unroll") \
      for (int g = 0; g < 4; ++g) (AM)[g] = MFMA(a, w1f[g][kt], (AM)[g]); \
    }
#define CELL1B(H1SRC, AM) \
    _Pragma("unroll") \
    for (int kt = 0; kt < 4; ++kt) { \
      const bf16x8 a = *(const bf16x8*)&(H1SRC)[kt * 512 + l * 8]; \
      _Pragma("unroll") \
      for (int g = 0; g < 4; ++g) (AM)[g] = MFMA(a, w1f[g][kt + 4], (AM)[g]); \
    }

// LSTM elementwise in scaled-c domain: gates ACC (i,f,o pre-scaled by log2e,
// g by 2log2e), CS = 2log2e*c_true.
#define ACT4(ACC, CS, DST) \
    _Pragma("unroll") \
    for (int r = 0; r < 4; ++r) { \
      const float iv = sig2((ACC)[0][r]); \
      const float fv = sig2((ACC)[1][r]); \
      const float tg = __builtin_amdgcn_rcpf(1.f + __builtin_amdgcn_exp2f((ACC)[2][r])); \
      const float ov = sig2((ACC)[3][r]); \
      const float gs = TWO_LOG2E - 2.f * TWO_LOG2E * tg; \
      const float cc = fv * (CS)[r] + iv * gs; \
      (CS)[r] = cc; \
      const float tc = __builtin_amdgcn_rcpf(1.f + __builtin_amdgcn_exp2f(cc)); \
      const float hv = ov - 2.f * ov * tc; \
      DST; \
    }

#define PROJ_MFMA(H1SRC, DACC) { \
    DACC = (float4_t){boutr, boutr, boutr, boutr}; \
    _Pragma("unroll") \
    for (int kt = 0; kt < 4; ++kt) { \
      const bf16x8 a  = *(const bf16x8*)&(H1SRC)[kt * 512 + l * 8]; \
      const bf16x8 bw = *(const bf16x8*)&woutF[(n_c * 4 + kt) * 512 + l * 8]; \
      DACC = MFMA(a, bw, DACC); \
    } \
  }
#define PROJ_FIN(XFDST, DACC) { \
    _Pragma("unroll") \
    for (int r = 0; r < 4; ++r) { \
      xr[r] += DACC[r]; \
      (XFDST)[xfb + r * 8] = f2bf(xr[r]); \
    } \
  }

  float4_t am1[4];            // s1's cell1 gates, pending act (crosses iters)
  INIT4(am1, b1r);

  __syncthreads();   // publish packing, xf seeds, h zeros

  #pragma unroll 1
  for (int t = 0; t < T; ++t) {
    // ===== R1: cell0h(s0) ; projMFMA(s0) ; act1(s1,t-1)->h1f1 ; projFIN =====
    float4_t acc0s0[4];
    INIT4(acc0s0, b0r);
    CELL0H(h0f0, acc0s0);
    if (t > 0) {
      float4_t dacc;
      if (w < 2) PROJ_MFMA(h1f0, dacc);
      ACT4(am1, c1s1, h1f1[hwb + r * 8] = f2bf(hv));
      if (w < 2) PROJ_FIN(xf0, dacc);
    }
    __syncthreads();

    // ===== R2: x-part(s0) ; cell0h(s1) ; projMFMA(s1) ; act0(s0)->h0f0 ; projFIN =====
    float4_t acc0s1[4];
    XPART(xf0, acc0s0);
    INIT4(acc0s1, b0r);
    CELL0H(h0f1, acc0s1);
    {
      float4_t dacc;
      const bool pw = (w >= 2 && w < 4 && t > 0);
      if (pw) PROJ_MFMA(h1f1, dacc);
      ACT4(acc0s0, c0s0, h0f0[hwb + r * 8] = f2bf(hv));
      if (pw) PROJ_FIN(xf1, dacc);
    }
    __syncthreads();

    // ===== R3: stores x0(t) ; cell1(s0)->am0 ; x-part(s1) ; act0(s1)->h0f1 =====
    if (w < 2 && t > 0) {
      const long ob = obase0 + (long)t * 32;
      #pragma unroll
      for (int r = 0; r < 4; ++r) out[ob + r * rowStride] = xr[r];
    }
    float4_t am0[4];
    INIT4(am0, b1r);
    CELL1A(h0f0, am0);
    XPART(xf1, acc0s1);
    CELL1B(h1f0, am0);
    ACT4(acc0s1, c0s1, h0f1[hwb + r * 8] = f2bf(hv));
    __syncthreads();

    // ===== R4: stores x1(t) ; cell1(s1)->am1 ; act1(s0,am0)->h1f0 =====
    if (w >= 2 && w < 4 && t > 0) {
      const long ob = obase0 + (long)t * 32;
      #pragma unroll
      for (int r = 0; r < 4; ++r) out[ob + r * rowStride] = xr[r];
    }
    INIT4(am1, b1r);
    CELL1A(h0f1, am1);
    CELL1B(h1f1, am1);
    ACT4(am0, c1s0, h1f0[hwb + r * 8] = f2bf(hv));
    __syncthreads();
  }

  // ===== Epilogue: act1(s1,T-1) -> h1f1, then final projections x(T) =====
  ACT4(am1, c1s1, h1f1[hwb + r * 8] = f2bf(hv));
  if (w < 2) {   // x0(T): h1f0 holds h1(T-1), published at last R4 barrier
    float4_t dacc;
    PROJ_MFMA(h1f0, dacc);
    const long ob = obase0 + (long)T * 32;
    #pragma unroll
    for (int r = 0; r < 4; ++r) {
      xr[r] += dacc[r];
      out[ob + r * rowStride] = xr[r];
    }
  }
  __syncthreads();   // publish h1f1
  if (w >= 2 && w < 4) {   // x1(T)
    float4_t dacc;
    PROJ_MFMA(h1f1, dacc);
    const long ob = obase0 + (long)T * 32;
    #pragma unroll
    for (int r = 0; r < 4; ++r) {
      xr[r] += dacc[r];
      out[ob + r * rowStride] = xr[r];
    }
  }
}

extern "C" void kernel_launch(void* const* d_in, const int* in_sizes, int n_in,
                              void* d_out, int out_size, void* d_ws, size_t ws_size,
                              hipStream_t stream) {
  (void)n_in; (void)out_size; (void)d_ws; (void)ws_size;
  const float* x0   = (const float*)d_in[0];
  const float* W0   = (const float*)d_in[1];
  const float* b0   = (const float*)d_in[2];
  const float* W1   = (const float*)d_in[3];
  const float* b1   = (const float*)d_in[4];
  const float* Wout = (const float*)d_in[5];
  const float* bout = (const float*)d_in[6];
  const float* dts  = (const float*)d_in[7];
  const int*   nsp  = (const int*)d_in[8];
  float* out = (float*)d_out;

  const int B    = in_sizes[0] / 32;   // 8192
  const int grid = B / 32;             // 256 blocks, 32 batch rows each
  lstm_roll<<<dim3(grid), dim3(512), 0, stream>>>(x0, W0, b0, W1, b1, Wout, bout, dts, nsp, out);
}

// Round 13
// 2492.865 us; speedup vs baseline: 1.1237x; 1.1237x over previous
//
#include <hip/hip_runtime.h>
#include <hip/hip_bf16.h>

typedef __bf16  bf16x8  __attribute__((ext_vector_type(8)));
typedef short   short8_t __attribute__((ext_vector_type(8)));
typedef float   float4_t __attribute__((ext_vector_type(4)));

#define MFMA(a, b, c) __builtin_amdgcn_mfma_f32_16x16x32_bf16((a), (b), (c), 0, 0, 0)

#define LOG2E      1.4426950408889634f
#define TWO_LOG2E  2.8853900817779268f

#define PRIO1() __builtin_amdgcn_s_setprio(1)
#define PRIO0() __builtin_amdgcn_s_setprio(0)

__device__ __forceinline__ unsigned short f2bf(float f) {
  return __builtin_bit_cast(unsigned short, static_cast<__bf16>(f));  // HW cvt, RTE
}
// x pre-scaled by LOG2E
__device__ __forceinline__ float sig2(float x) {
  return __builtin_amdgcn_rcpf(1.f + __builtin_amdgcn_exp2f(-x));
}

// 256 blocks x 512 threads (8 waves), 32 rows/block, TWO 16-row streams
// phase-shifted one region apart; trans equalized ~40/region via deferred
// act1; c-state in the 2*log2e-scaled domain. R11 schedule + statement order
// VERBATIM (R12 proved the natural MFMA/trans interleave beats MFMA-first);
// only change: s_setprio(1) around MFMA clusters so the issue port favors
// the MFMA-issuing wave while its SIMD-mate runs the trans burst (T5).
// Per step, 4 __syncthreads:
//   R1: cell0h(s0,t) ; act1(s1,t-1)->h1f1 ; proj(s0) [w<2]
//   R2: x-part+act0(s0)->h0f0 ; cell0h(s1,t) ; proj(s1) [w=2,3]
//   R3: stores x0(t) ; cell1(s0)->am0 ; x-part+act0(s1)->h0f1
//   R4: stores x1(t) ; act1(s0)->h1f0 ; cell1(s1)->am1
__global__ __launch_bounds__(512, 2) void lstm_roll(
    const float* __restrict__ x0,  const float* __restrict__ W0,
    const float* __restrict__ b0v, const float* __restrict__ W1,
    const float* __restrict__ b1v, const float* __restrict__ Wout,
    const float* __restrict__ bout, const float* __restrict__ dts,
    const int* __restrict__ nsp,   float* __restrict__ out)
{
  __shared__ __align__(16) unsigned short w0h[8 * 4 * 4 * 512];  // 128 KiB W0 h-part B-frags [w][g][kt]
  __shared__ __align__(16) unsigned short woutF[2 * 4 * 512];    //   8 KiB Wout B-frags (dts*DT folded)
  __shared__ __align__(16) unsigned short h0f0[4 * 512];         //   4 KiB h0 A-frags, stream0
  __shared__ __align__(16) unsigned short h0f1[4 * 512];         //   4 KiB h0 A-frags, stream1
  __shared__ __align__(16) unsigned short h1f0[4 * 512];         //   4 KiB h1 A-frags, stream0
  __shared__ __align__(16) unsigned short h1f1[4 * 512];         //   4 KiB h1 A-frags, stream1
  __shared__ __align__(16) unsigned short xf0[512];              //   1 KiB x A-frag, stream0
  __shared__ __align__(16) unsigned short xf1[512];              //   1 KiB x A-frag, stream1

  const int tid = threadIdx.x;
  const int w   = tid >> 6;
  const int l   = tid & 63;
  const int lm  = l & 15;
  const int lh  = l >> 4;
  const int T   = nsp[0];
  const long rowStride = (long)(T + 1) * 32;
  const long bbase = (long)blockIdx.x * 32;

  // ---------------- weight gather / packing (once) ----------------
  bf16x8 w0x[4];       // W0 x-part B-frags (K=32)
  bf16x8 w1f[4][8];    // W1 B-frags (K=256; kt 0..3 h0-part, 4..7 h1-part)
  #pragma unroll
  for (int g = 0; g < 4; ++g) {
    const float sc = (g == 2) ? TWO_LOG2E : LOG2E;
    const int col = g * 128 + w * 16 + lm;
    {
      short8_t t8;
      #pragma unroll
      for (int e = 0; e < 8; ++e) t8[e] = (short)f2bf(sc * W0[(lh * 8 + e) * 512 + col]);
      w0x[g] = __builtin_bit_cast(bf16x8, t8);
    }
    #pragma unroll
    for (int kt = 0; kt < 8; ++kt) {
      short8_t t8;
      #pragma unroll
      for (int e = 0; e < 8; ++e) t8[e] = (short)f2bf(sc * W1[(kt * 32 + lh * 8 + e) * 512 + col]);
      w1f[g][kt] = __builtin_bit_cast(bf16x8, t8);
    }
    #pragma unroll
    for (int kt = 0; kt < 4; ++kt) {
      const int base = (((w * 4 + g) * 4) + kt) * 512 + l * 8;
      #pragma unroll
      for (int e = 0; e < 8; ++e)
        w0h[base + e] = f2bf(sc * W0[(32 + kt * 32 + lh * 8 + e) * 512 + col]);
    }
  }
  { // Wout B-frags with dts*DT folded in
    const int n = w & 1, kt = w >> 1;
    if (kt < 4) {
      const float csc = dts[n * 16 + lm] * 0.01f;
      const int base = (n * 4 + kt) * 512 + l * 8;
      #pragma unroll
      for (int e = 0; e < 8; ++e)
        woutF[base + e] = f2bf(csc * Wout[(kt * 32 + lh * 8 + e) * 32 + (n * 16 + lm)]);
    }
  }
  float b0r[4], b1r[4];
  #pragma unroll
  for (int g = 0; g < 4; ++g) {
    const float sc = (g == 2) ? TWO_LOG2E : LOG2E;
    b0r[g] = sc * b0v[g * 128 + w * 16 + lm];
    b1r[g] = sc * b1v[g * 128 + w * 16 + lm];
  }

  // proj/store mapping: waves 0,1 -> stream0 (n_c = w&1); waves 2,3 -> stream1
  const int S_w = (w >> 1) & 1;
  const int n_c = w & 1;
  float boutr = 0.f, xr[4] = {0.f, 0.f, 0.f, 0.f};
  long obase0 = 0;
  int  xfb = 0;
  if (w < 4) {
    boutr = bout[n_c * 16 + lm] * dts[n_c * 16 + lm] * 0.01f;
    const int kin = n_c * 16 + lm;
    xfb = (lh * 4 + 16 * (kin >> 3)) * 8 + (kin & 7);
    obase0 = (bbase + S_w * 16 + lh * 4) * rowStride + (n_c * 16 + lm);
    unsigned short* xfS = S_w ? xf1 : xf0;
    #pragma unroll
    for (int r = 0; r < 4; ++r) {
      xr[r] = x0[(bbase + S_w * 16 + lh * 4 + r) * 32 + n_c * 16 + lm];
      out[obase0 + r * rowStride] = xr[r];   // trajectory t = 0
      xfS[xfb + r * 8] = f2bf(xr[r]);        // seed xf(0)
    }
  }
  for (int i = tid; i < 4 * 512; i += 512) {
    h0f0[i] = 0; h0f1[i] = 0; h1f0[i] = 0; h1f1[i] = 0;
  }

  // h-write scatter base (per-stream fragment layout; kt = w>>1)
  const int hwb = (w >> 1) * 512 +
                  (lh * 4 + 16 * (2 * (w & 1) + ((lm >> 3) & 1))) * 8 + (lm & 7);

  // c-states live in the 2*log2e-scaled domain
  float4_t c0s0 = {0.f,0.f,0.f,0.f}, c0s1 = {0.f,0.f,0.f,0.f};
  float4_t c1s0 = {0.f,0.f,0.f,0.f}, c1s1 = {0.f,0.f,0.f,0.f};

#define INIT4(ACC, B) \
    _Pragma("unroll") \
    for (int g = 0; g < 4; ++g) (ACC)[g] = (float4_t){(B)[g], (B)[g], (B)[g], (B)[g]};

#define CELL0H(HSRC, ACC) \
    _Pragma("unroll") \
    for (int kt = 0; kt < 4; ++kt) { \
      const bf16x8 a = *(const bf16x8*)&(HSRC)[kt * 512 + l * 8]; \
      _Pragma("unroll") \
      for (int g = 0; g < 4; ++g) { \
        const bf16x8 bw = *(const bf16x8*)&w0h[(((w * 4 + g) * 4) + kt) * 512 + l * 8]; \
        (ACC)[g] = MFMA(a, bw, (ACC)[g]); \
      } \
    }

#define XPART(XSRC, ACC) { \
    const bf16x8 ax = *(const bf16x8*)&(XSRC)[l * 8]; \
    _Pragma("unroll") \
    for (int g = 0; g < 4; ++g) (ACC)[g] = MFMA(ax, w0x[g], (ACC)[g]); \
  }

#define CELL1A(H0SRC, AM) \
    _Pragma("unroll") \
    for (int kt = 0; kt < 4; ++kt) { \
      const bf16x8 a = *(const bf16x8*)&(H0SRC)[kt * 512 + l * 8]; \
      _Pragma("unroll") \
      for (int g = 0; g < 4; ++g) (AM)[g] = MFMA(a, w1f[g][kt], (AM)[g]); \
    }
#define CELL1B(H1SRC, AM) \
    _Pragma("unroll") \
    for (int kt = 0; kt < 4; ++kt) { \
      const bf16x8 a = *(const bf16x8*)&(H1SRC)[kt * 512 + l * 8]; \
      _Pragma("unroll") \
      for (int g = 0; g < 4; ++g) (AM)[g] = MFMA(a, w1f[g][kt + 4], (AM)[g]); \
    }

// LSTM elementwise in scaled-c domain: gates ACC (i,f,o pre-scaled by log2e,
// g by 2log2e), CS = 2log2e*c_true.
#define ACT4(ACC, CS, DST) \
    _Pragma("unroll") \
    for (int r = 0; r < 4; ++r) { \
      const float iv = sig2((ACC)[0][r]); \
      const float fv = sig2((ACC)[1][r]); \
      const float tg = __builtin_amdgcn_rcpf(1.f + __builtin_amdgcn_exp2f((ACC)[2][r])); \
      const float ov = sig2((ACC)[3][r]); \
      const float gs = TWO_LOG2E - 2.f * TWO_LOG2E * tg; \
      const float cc = fv * (CS)[r] + iv * gs; \
      (CS)[r] = cc; \
      const float tc = __builtin_amdgcn_rcpf(1.f + __builtin_amdgcn_exp2f(cc)); \
      const float hv = ov - 2.f * ov * tc; \
      DST; \
    }

#define PROJ(H1SRC, XFDST) { \
    float4_t dacc = (float4_t){boutr, boutr, boutr, boutr}; \
    PRIO1(); \
    _Pragma("unroll") \
    for (int kt = 0; kt < 4; ++kt) { \
      const bf16x8 a  = *(const bf16x8*)&(H1SRC)[kt * 512 + l * 8]; \
      const bf16x8 bw = *(const bf16x8*)&woutF[(n_c * 4 + kt) * 512 + l * 8]; \
      dacc = MFMA(a, bw, dacc); \
    } \
    PRIO0(); \
    _Pragma("unroll") \
    for (int r = 0; r < 4; ++r) { \
      xr[r] += dacc[r]; \
      (XFDST)[xfb + r * 8] = f2bf(xr[r]); \
    } \
  }

  float4_t am1[4];            // s1's cell1 gates, pending act (crosses iters)
  INIT4(am1, b1r);

  __syncthreads();   // publish packing, xf seeds, h zeros

  #pragma unroll 1
  for (int t = 0; t < T; ++t) {
    // ===== R1: cell0h(s0) ; act1(s1,t-1) -> h1f1 ; proj(s0) =====
    float4_t acc0s0[4];
    INIT4(acc0s0, b0r);
    PRIO1();
    CELL0H(h0f0, acc0s0);
    PRIO0();
    if (t > 0) {
      ACT4(am1, c1s1, h1f1[hwb + r * 8] = f2bf(hv));
      if (w < 2) PROJ(h1f0, xf0);
    }
    __syncthreads();

    // ===== R2: x-part+act0(s0) -> h0f0 ; cell0h(s1) ; proj(s1) =====
    float4_t acc0s1[4];
    PRIO1();
    XPART(xf0, acc0s0);
    INIT4(acc0s1, b0r);
    CELL0H(h0f1, acc0s1);
    PRIO0();
    ACT4(acc0s0, c0s0, h0f0[hwb + r * 8] = f2bf(hv));
    if (w >= 2 && w < 4 && t > 0) PROJ(h1f1, xf1);
    __syncthreads();

    // ===== R3: stores x0(t) ; cell1(s0) -> am0 ; x-part+act0(s1) -> h0f1 =====
    if (w < 2 && t > 0) {
      const long ob = obase0 + (long)t * 32;
      #pragma unroll
      for (int r = 0; r < 4; ++r) out[ob + r * rowStride] = xr[r];
    }
    float4_t am0[4];
    INIT4(am0, b1r);
    PRIO1();
    CELL1A(h0f0, am0);
    XPART(xf1, acc0s1);
    PRIO0();
    ACT4(acc0s1, c0s1, h0f1[hwb + r * 8] = f2bf(hv));
    PRIO1();
    CELL1B(h1f0, am0);
    PRIO0();
    __syncthreads();

    // ===== R4: stores x1(t) ; act1(s0) -> h1f0 ; cell1(s1) -> am1 =====
    if (w >= 2 && w < 4 && t > 0) {
      const long ob = obase0 + (long)t * 32;
      #pragma unroll
      for (int r = 0; r < 4; ++r) out[ob + r * rowStride] = xr[r];
    }
    ACT4(am0, c1s0, h1f0[hwb + r * 8] = f2bf(hv));
    INIT4(am1, b1r);
    PRIO1();
    CELL1A(h0f1, am1);
    CELL1B(h1f1, am1);
    PRIO0();
    __syncthreads();
  }

  // ===== Epilogue: act1(s1,T-1) -> h1f1, then final projections x(T) =====
  ACT4(am1, c1s1, h1f1[hwb + r * 8] = f2bf(hv));
  if (w < 2) {   // x0(T): h1f0 holds h1(T-1), published at last R4 barrier
    float4_t dacc = (float4_t){boutr, boutr, boutr, boutr};
    #pragma unroll
    for (int kt = 0; kt < 4; ++kt) {
      const bf16x8 a  = *(const bf16x8*)&h1f0[kt * 512 + l * 8];
      const bf16x8 bw = *(const bf16x8*)&woutF[(n_c * 4 + kt) * 512 + l * 8];
      dacc = MFMA(a, bw, dacc);
    }
    const long ob = obase0 + (long)T * 32;
    #pragma unroll
    for (int r = 0; r < 4; ++r) {
      xr[r] += dacc[r];
      out[ob + r * rowStride] = xr[r];
    }
  }
  __syncthreads();   // publish h1f1
  if (w >= 2 && w < 4) {   // x1(T)
    float4_t dacc = (float4_t){boutr, boutr, boutr, boutr};
    #pragma unroll
    for (int kt = 0; kt < 4; ++kt) {
      const bf16x8 a  = *(const bf16x8*)&h1f1[kt * 512 + l * 8];
      const bf16x8 bw = *(const bf16x8*)&woutF[(n_c * 4 + kt) * 512 + l * 8];
      dacc = MFMA(a, bw, dacc);
    }
    const long ob = obase0 + (long)T * 32;
    #pragma unroll
    for (int r = 0; r < 4; ++r) {
      xr[r] += dacc[r];
      out[ob + r * rowStride] = xr[r];
    }
  }
}

extern "C" void kernel_launch(void* const* d_in, const int* in_sizes, int n_in,
                              void* d_out, int out_size, void* d_ws, size_t ws_size,
                              hipStream_t stream) {
  (void)n_in; (void)out_size; (void)d_ws; (void)ws_size;
  const float* x0   = (const float*)d_in[0];
  const float* W0   = (const float*)d_in[1];
  const float* b0   = (const float*)d_in[2];
  const float* W1   = (const float*)d_in[3];
  const float* b1   = (const float*)d_in[4];
  const float* Wout = (const float*)d_in[5];
  const float* bout = (const float*)d_in[6];
  const float* dts  = (const float*)d_in[7];
  const int*   nsp  = (const int*)d_in[8];
  float* out = (float*)d_out;

  const int B    = in_sizes[0] / 32;   // 8192
  const int grid = B / 32;             // 256 blocks, 32 batch rows each
  lstm_roll<<<dim3(grid), dim3(512), 0, stream>>>(x0, W0, b0, W1, b1, Wout, bout, dts, nsp, out);
}

// Round 14
// 2437.984 us; speedup vs baseline: 1.1490x; 1.0225x over previous
//
#include <hip/hip_runtime.h>
#include <hip/hip_bf16.h>

typedef __bf16  bf16x8  __attribute__((ext_vector_type(8)));
typedef short   short8_t __attribute__((ext_vector_type(8)));
typedef float   float4_t __attribute__((ext_vector_type(4)));

#define MFMA(a, b, c) __builtin_amdgcn_mfma_f32_16x16x32_bf16((a), (b), (c), 0, 0, 0)

#define LOG2E      1.4426950408889634f
#define TWO_LOG2E  2.8853900817779268f

__device__ __forceinline__ unsigned short f2bf(float f) {
  return __builtin_bit_cast(unsigned short, static_cast<__bf16>(f));  // HW cvt, RTE
}

// 256 blocks x 512 threads (8 waves), 32 rows/block, TWO 16-row streams
// phase-shifted one region apart; trans equalized ~40/region via deferred
// act1 (gates ride MFMA C-regs across one barrier); c-state in the
// 2*log2e-scaled domain. ACT4 uses PAIRED reciprocals: 1/A,1/B = B*rcp(AB),
// A*rcp(AB) -- exact algebra, cuts rcp count 20->10 per ACT4 (trans stream
// 160->120 per wave/step). R11 schedule verbatim; no setprio (R13 convicted),
// no asm barriers (R5/R10), natural MFMA/trans interleave (R12).
// Per step, 4 __syncthreads:
//   R1: cell0h(s0,t) ; act1(s1,t-1)->h1f1 ; proj(s0) [w<2]
//   R2: x-part+act0(s0)->h0f0 ; cell0h(s1,t) ; proj(s1) [w=2,3]
//   R3: stores x0(t) ; cell1(s0)->am0 ; x-part+act0(s1)->h0f1
//   R4: stores x1(t) ; act1(s0)->h1f0 ; cell1(s1)->am1
__global__ __launch_bounds__(512, 2) void lstm_roll(
    const float* __restrict__ x0,  const float* __restrict__ W0,
    const float* __restrict__ b0v, const float* __restrict__ W1,
    const float* __restrict__ b1v, const float* __restrict__ Wout,
    const float* __restrict__ bout, const float* __restrict__ dts,
    const int* __restrict__ nsp,   float* __restrict__ out)
{
  __shared__ __align__(16) unsigned short w0h[8 * 4 * 4 * 512];  // 128 KiB W0 h-part B-frags [w][g][kt]
  __shared__ __align__(16) unsigned short woutF[2 * 4 * 512];    //   8 KiB Wout B-frags (dts*DT folded)
  __shared__ __align__(16) unsigned short h0f0[4 * 512];         //   4 KiB h0 A-frags, stream0
  __shared__ __align__(16) unsigned short h0f1[4 * 512];         //   4 KiB h0 A-frags, stream1
  __shared__ __align__(16) unsigned short h1f0[4 * 512];         //   4 KiB h1 A-frags, stream0
  __shared__ __align__(16) unsigned short h1f1[4 * 512];         //   4 KiB h1 A-frags, stream1
  __shared__ __align__(16) unsigned short xf0[512];              //   1 KiB x A-frag, stream0
  __shared__ __align__(16) unsigned short xf1[512];              //   1 KiB x A-frag, stream1

  const int tid = threadIdx.x;
  const int w   = tid >> 6;
  const int l   = tid & 63;
  const int lm  = l & 15;
  const int lh  = l >> 4;
  const int T   = nsp[0];
  const long rowStride = (long)(T + 1) * 32;
  const long bbase = (long)blockIdx.x * 32;

  // ---------------- weight gather / packing (once) ----------------
  bf16x8 w0x[4];       // W0 x-part B-frags (K=32)
  bf16x8 w1f[4][8];    // W1 B-frags (K=256; kt 0..3 h0-part, 4..7 h1-part)
  #pragma unroll
  for (int g = 0; g < 4; ++g) {
    const float sc = (g == 2) ? TWO_LOG2E : LOG2E;
    const int col = g * 128 + w * 16 + lm;
    {
      short8_t t8;
      #pragma unroll
      for (int e = 0; e < 8; ++e) t8[e] = (short)f2bf(sc * W0[(lh * 8 + e) * 512 + col]);
      w0x[g] = __builtin_bit_cast(bf16x8, t8);
    }
    #pragma unroll
    for (int kt = 0; kt < 8; ++kt) {
      short8_t t8;
      #pragma unroll
      for (int e = 0; e < 8; ++e) t8[e] = (short)f2bf(sc * W1[(kt * 32 + lh * 8 + e) * 512 + col]);
      w1f[g][kt] = __builtin_bit_cast(bf16x8, t8);
    }
    #pragma unroll
    for (int kt = 0; kt < 4; ++kt) {
      const int base = (((w * 4 + g) * 4) + kt) * 512 + l * 8;
      #pragma unroll
      for (int e = 0; e < 8; ++e)
        w0h[base + e] = f2bf(sc * W0[(32 + kt * 32 + lh * 8 + e) * 512 + col]);
    }
  }
  { // Wout B-frags with dts*DT folded in
    const int n = w & 1, kt = w >> 1;
    if (kt < 4) {
      const float csc = dts[n * 16 + lm] * 0.01f;
      const int base = (n * 4 + kt) * 512 + l * 8;
      #pragma unroll
      for (int e = 0; e < 8; ++e)
        woutF[base + e] = f2bf(csc * Wout[(kt * 32 + lh * 8 + e) * 32 + (n * 16 + lm)]);
    }
  }
  float b0r[4], b1r[4];
  #pragma unroll
  for (int g = 0; g < 4; ++g) {
    const float sc = (g == 2) ? TWO_LOG2E : LOG2E;
    b0r[g] = sc * b0v[g * 128 + w * 16 + lm];
    b1r[g] = sc * b1v[g * 128 + w * 16 + lm];
  }

  // proj/store mapping: waves 0,1 -> stream0 (n_c = w&1); waves 2,3 -> stream1
  const int S_w = (w >> 1) & 1;
  const int n_c = w & 1;
  float boutr = 0.f, xr[4] = {0.f, 0.f, 0.f, 0.f};
  long obase0 = 0;
  int  xfb = 0;
  if (w < 4) {
    boutr = bout[n_c * 16 + lm] * dts[n_c * 16 + lm] * 0.01f;
    const int kin = n_c * 16 + lm;
    xfb = (lh * 4 + 16 * (kin >> 3)) * 8 + (kin & 7);
    obase0 = (bbase + S_w * 16 + lh * 4) * rowStride + (n_c * 16 + lm);
    unsigned short* xfS = S_w ? xf1 : xf0;
    #pragma unroll
    for (int r = 0; r < 4; ++r) {
      xr[r] = x0[(bbase + S_w * 16 + lh * 4 + r) * 32 + n_c * 16 + lm];
      out[obase0 + r * rowStride] = xr[r];   // trajectory t = 0
      xfS[xfb + r * 8] = f2bf(xr[r]);        // seed xf(0)
    }
  }
  for (int i = tid; i < 4 * 512; i += 512) {
    h0f0[i] = 0; h0f1[i] = 0; h1f0[i] = 0; h1f1[i] = 0;
  }

  // h-write scatter base (per-stream fragment layout; kt = w>>1)
  const int hwb = (w >> 1) * 512 +
                  (lh * 4 + 16 * (2 * (w & 1) + ((lm >> 3) & 1))) * 8 + (lm & 7);

  // c-states live in the 2*log2e-scaled domain
  float4_t c0s0 = {0.f,0.f,0.f,0.f}, c0s1 = {0.f,0.f,0.f,0.f};
  float4_t c1s0 = {0.f,0.f,0.f,0.f}, c1s1 = {0.f,0.f,0.f,0.f};

#define INIT4(ACC, B) \
    _Pragma("unroll") \
    for (int g = 0; g < 4; ++g) (ACC)[g] = (float4_t){(B)[g], (B)[g], (B)[g], (B)[g]};

#define CELL0H(HSRC, ACC) \
    _Pragma("unroll") \
    for (int kt = 0; kt < 4; ++kt) { \
      const bf16x8 a = *(const bf16x8*)&(HSRC)[kt * 512 + l * 8]; \
      _Pragma("unroll") \
      for (int g = 0; g < 4; ++g) { \
        const bf16x8 bw = *(const bf16x8*)&w0h[(((w * 4 + g) * 4) + kt) * 512 + l * 8]; \
        (ACC)[g] = MFMA(a, bw, (ACC)[g]); \
      } \
    }

#define XPART(XSRC, ACC) { \
    const bf16x8 ax = *(const bf16x8*)&(XSRC)[l * 8]; \
    _Pragma("unroll") \
    for (int g = 0; g < 4; ++g) (ACC)[g] = MFMA(ax, w0x[g], (ACC)[g]); \
  }

#define CELL1A(H0SRC, AM) \
    _Pragma("unroll") \
    for (int kt = 0; kt < 4; ++kt) { \
      const bf16x8 a = *(const bf16x8*)&(H0SRC)[kt * 512 + l * 8]; \
      _Pragma("unroll") \
      for (int g = 0; g < 4; ++g) (AM)[g] = MFMA(a, w1f[g][kt], (AM)[g]); \
    }
#define CELL1B(H1SRC, AM) \
    _Pragma("unroll") \
    for (int kt = 0; kt < 4; ++kt) { \
      const bf16x8 a = *(const bf16x8*)&(H1SRC)[kt * 512 + l * 8]; \
      _Pragma("unroll") \
      for (int g = 0; g < 4; ++g) (AM)[g] = MFMA(a, w1f[g][kt + 4], (AM)[g]); \
    }

// LSTM elementwise in scaled-c domain with PAIRED reciprocals.
// Gates pre-scaled: i,f,o by log2e, g by 2log2e; CS = 2log2e*c_true.
// 1/A and 1/B computed as B*rcp(A*B), A*rcp(A*B): exact, halves rcp count.
// exp2 cannot overflow here (|preact| << 128) so A*B is finite.
#define ACT4(ACC, CS, DST) { \
    float iv4[4], fv4[4], tg4[4], ov4[4], Ac4[4]; \
    _Pragma("unroll") \
    for (int r = 0; r < 4; ++r) { \
      const float Ai = 1.f + __builtin_amdgcn_exp2f(-(ACC)[0][r]); \
      const float Af = 1.f + __builtin_amdgcn_exp2f(-(ACC)[1][r]); \
      const float Ag = 1.f + __builtin_amdgcn_exp2f((ACC)[2][r]); \
      const float Ao = 1.f + __builtin_amdgcn_exp2f(-(ACC)[3][r]); \
      const float rif = __builtin_amdgcn_rcpf(Ai * Af); \
      const float rgo = __builtin_amdgcn_rcpf(Ag * Ao); \
      iv4[r] = Af * rif;  fv4[r] = Ai * rif; \
      tg4[r] = Ao * rgo;  ov4[r] = Ag * rgo; \
    } \
    _Pragma("unroll") \
    for (int r = 0; r < 4; ++r) { \
      const float gs = TWO_LOG2E - 2.f * TWO_LOG2E * tg4[r]; \
      const float cc = fv4[r] * (CS)[r] + iv4[r] * gs; \
      (CS)[r] = cc; \
      Ac4[r] = 1.f + __builtin_amdgcn_exp2f(cc); \
    } \
    const float rc01 = __builtin_amdgcn_rcpf(Ac4[0] * Ac4[1]); \
    const float rc23 = __builtin_amdgcn_rcpf(Ac4[2] * Ac4[3]); \
    const float tcv[4] = { Ac4[1] * rc01, Ac4[0] * rc01, \
                           Ac4[3] * rc23, Ac4[2] * rc23 }; \
    _Pragma("unroll") \
    for (int r = 0; r < 4; ++r) { \
      const float hv = ov4[r] - 2.f * ov4[r] * tcv[r]; \
      DST; \
    } \
  }

#define PROJ(H1SRC, XFDST) { \
    float4_t dacc = (float4_t){boutr, boutr, boutr, boutr}; \
    _Pragma("unroll") \
    for (int kt = 0; kt < 4; ++kt) { \
      const bf16x8 a  = *(const bf16x8*)&(H1SRC)[kt * 512 + l * 8]; \
      const bf16x8 bw = *(const bf16x8*)&woutF[(n_c * 4 + kt) * 512 + l * 8]; \
      dacc = MFMA(a, bw, dacc); \
    } \
    _Pragma("unroll") \
    for (int r = 0; r < 4; ++r) { \
      xr[r] += dacc[r]; \
      (XFDST)[xfb + r * 8] = f2bf(xr[r]); \
    } \
  }

  float4_t am1[4];            // s1's cell1 gates, pending act (crosses iters)
  INIT4(am1, b1r);

  __syncthreads();   // publish packing, xf seeds, h zeros

  #pragma unroll 1
  for (int t = 0; t < T; ++t) {
    // ===== R1: cell0h(s0) ; act1(s1,t-1) -> h1f1 ; proj(s0) =====
    float4_t acc0s0[4];
    INIT4(acc0s0, b0r);
    CELL0H(h0f0, acc0s0);
    if (t > 0) {
      ACT4(am1, c1s1, h1f1[hwb + r * 8] = f2bf(hv));
      if (w < 2) PROJ(h1f0, xf0);
    }
    __syncthreads();

    // ===== R2: x-part+act0(s0) -> h0f0 ; cell0h(s1) ; proj(s1) =====
    float4_t acc0s1[4];
    XPART(xf0, acc0s0);
    INIT4(acc0s1, b0r);
    CELL0H(h0f1, acc0s1);
    ACT4(acc0s0, c0s0, h0f0[hwb + r * 8] = f2bf(hv));
    if (w >= 2 && w < 4 && t > 0) PROJ(h1f1, xf1);
    __syncthreads();

    // ===== R3: stores x0(t) ; cell1(s0) -> am0 ; x-part+act0(s1) -> h0f1 =====
    if (w < 2 && t > 0) {
      const long ob = obase0 + (long)t * 32;
      #pragma unroll
      for (int r = 0; r < 4; ++r) out[ob + r * rowStride] = xr[r];
    }
    float4_t am0[4];
    INIT4(am0, b1r);
    CELL1A(h0f0, am0);
    XPART(xf1, acc0s1);
    ACT4(acc0s1, c0s1, h0f1[hwb + r * 8] = f2bf(hv));
    CELL1B(h1f0, am0);
    __syncthreads();

    // ===== R4: stores x1(t) ; act1(s0) -> h1f0 ; cell1(s1) -> am1 =====
    if (w >= 2 && w < 4 && t > 0) {
      const long ob = obase0 + (long)t * 32;
      #pragma unroll
      for (int r = 0; r < 4; ++r) out[ob + r * rowStride] = xr[r];
    }
    ACT4(am0, c1s0, h1f0[hwb + r * 8] = f2bf(hv));
    INIT4(am1, b1r);
    CELL1A(h0f1, am1);
    CELL1B(h1f1, am1);
    __syncthreads();
  }

  // ===== Epilogue: act1(s1,T-1) -> h1f1, then final projections x(T) =====
  ACT4(am1, c1s1, h1f1[hwb + r * 8] = f2bf(hv));
  if (w < 2) {   // x0(T): h1f0 holds h1(T-1), published at last R4 barrier
    float4_t dacc = (float4_t){boutr, boutr, boutr, boutr};
    #pragma unroll
    for (int kt = 0; kt < 4; ++kt) {
      const bf16x8 a  = *(const bf16x8*)&h1f0[kt * 512 + l * 8];
      const bf16x8 bw = *(const bf16x8*)&woutF[(n_c * 4 + kt) * 512 + l * 8];
      dacc = MFMA(a, bw, dacc);
    }
    const long ob = obase0 + (long)T * 32;
    #pragma unroll
    for (int r = 0; r < 4; ++r) {
      xr[r] += dacc[r];
      out[ob + r * rowStride] = xr[r];
    }
  }
  __syncthreads();   // publish h1f1
  if (w >= 2 && w < 4) {   // x1(T)
    float4_t dacc = (float4_t){boutr, boutr, boutr, boutr};
    #pragma unroll
    for (int kt = 0; kt < 4; ++kt) {
      const bf16x8 a  = *(const bf16x8*)&h1f1[kt * 512 + l * 8];
      const bf16x8 bw = *(const bf16x8*)&woutF[(n_c * 4 + kt) * 512 + l * 8];
      dacc = MFMA(a, bw, dacc);
    }
    const long ob = obase0 + (long)T * 32;
    #pragma unroll
    for (int r = 0; r < 4; ++r) {
      xr[r] += dacc[r];
      out[ob + r * rowStride] = xr[r];
    }
  }
}

extern "C" void kernel_launch(void* const* d_in, const int* in_sizes, int n_in,
                              void* d_out, int out_size, void* d_ws, size_t ws_size,
                              hipStream_t stream) {
  (void)n_in; (void)out_size; (void)d_ws; (void)ws_size;
  const float* x0   = (const float*)d_in[0];
  const float* W0   = (const float*)d_in[1];
  const float* b0   = (const float*)d_in[2];
  const float* W1   = (const float*)d_in[3];
  const float* b1   = (const float*)d_in[4];
  const float* Wout = (const float*)d_in[5];
  const float* bout = (const float*)d_in[6];
  const float* dts  = (const float*)d_in[7];
  const int*   nsp  = (const int*)d_in[8];
  float* out = (float*)d_out;

  const int B    = in_sizes[0] / 32;   // 8192
  const int grid = B / 32;             // 256 blocks, 32 batch rows each
  lstm_roll<<<dim3(grid), dim3(512), 0, stream>>>(x0, W0, b0, W1, b1, Wout, bout, dts, nsp, out);
}

// Round 15
// 2215.742 us; speedup vs baseline: 1.2642x; 1.1003x over previous
//
#include <hip/hip_runtime.h>
#include <hip/hip_bf16.h>

typedef __bf16  bf16x8  __attribute__((ext_vector_type(8)));
typedef short   short8_t __attribute__((ext_vector_type(8)));
typedef float   float4_t __attribute__((ext_vector_type(4)));

#define MFMA(a, b, c) __builtin_amdgcn_mfma_f32_16x16x32_bf16((a), (b), (c), 0, 0, 0)

#define LOG2E      1.4426950408889634f
#define TWO_LOG2E  2.8853900817779268f

__device__ __forceinline__ unsigned short f2bf(float f) {
  return __builtin_bit_cast(unsigned short, static_cast<__bf16>(f));  // HW cvt, RTE
}
// x pre-scaled by LOG2E
__device__ __forceinline__ float sig2(float x) {
  return __builtin_amdgcn_rcpf(1.f + __builtin_amdgcn_exp2f(-x));
}

// R11 verbatim — the validated optimum (2632 us rocprof / 2217 us bench).
// 256 blocks x 512 threads (8 waves), 32 rows/block, TWO 16-row streams
// phase-shifted one region apart. Trans work equalized at ~40 ops/region by
// deferring each stream's act1 one region past its cell1 MFMAs (gates ride
// in MFMA C-registers across the barrier). c-state kept in the 2*log2e-scaled
// domain. Natural MFMA/trans interleave (R12 convicted MFMA-first), plain
// __syncthreads (R5/R10 convicted asm lgkm-barrier), no setprio (R13),
// independent per-element trans chains (R14 convicted paired rcp).
// Per step, 4 __syncthreads:
//   R1: cell0h(s0,t) 16 MFMA ; act1(s1,t-1) from am1 -> h1f1 ; proj(s0) [w<2]
//   R2: x-part+act0(s0) -> h0f0(t) ; cell0h(s1,t) ; proj(s1) [w=2,3]
//   R3: stores x0(t) ; cell1(s0) -> am0 (no act) ; x-part+act0(s1) -> h0f1(t)
//   R4: stores x1(t) ; act1(s0) from am0 -> h1f0 ; cell1(s1) -> am1 (no act)
__global__ __launch_bounds__(512, 2) void lstm_roll(
    const float* __restrict__ x0,  const float* __restrict__ W0,
    const float* __restrict__ b0v, const float* __restrict__ W1,
    const float* __restrict__ b1v, const float* __restrict__ Wout,
    const float* __restrict__ bout, const float* __restrict__ dts,
    const int* __restrict__ nsp,   float* __restrict__ out)
{
  __shared__ __align__(16) unsigned short w0h[8 * 4 * 4 * 512];  // 128 KiB W0 h-part B-frags [w][g][kt]
  __shared__ __align__(16) unsigned short woutF[2 * 4 * 512];    //   8 KiB Wout B-frags (dts*DT folded)
  __shared__ __align__(16) unsigned short h0f0[4 * 512];         //   4 KiB h0 A-frags, stream0
  __shared__ __align__(16) unsigned short h0f1[4 * 512];         //   4 KiB h0 A-frags, stream1
  __shared__ __align__(16) unsigned short h1f0[4 * 512];         //   4 KiB h1 A-frags, stream0
  __shared__ __align__(16) unsigned short h1f1[4 * 512];         //   4 KiB h1 A-frags, stream1
  __shared__ __align__(16) unsigned short xf0[512];              //   1 KiB x A-frag, stream0
  __shared__ __align__(16) unsigned short xf1[512];              //   1 KiB x A-frag, stream1

  const int tid = threadIdx.x;
  const int w   = tid >> 6;
  const int l   = tid & 63;
  const int lm  = l & 15;
  const int lh  = l >> 4;
  const int T   = nsp[0];
  const long rowStride = (long)(T + 1) * 32;
  const long bbase = (long)blockIdx.x * 32;

  // ---------------- weight gather / packing (once) ----------------
  bf16x8 w0x[4];       // W0 x-part B-frags (K=32)
  bf16x8 w1f[4][8];    // W1 B-frags (K=256; kt 0..3 h0-part, 4..7 h1-part)
  #pragma unroll
  for (int g = 0; g < 4; ++g) {
    const float sc = (g == 2) ? TWO_LOG2E : LOG2E;
    const int col = g * 128 + w * 16 + lm;
    {
      short8_t t8;
      #pragma unroll
      for (int e = 0; e < 8; ++e) t8[e] = (short)f2bf(sc * W0[(lh * 8 + e) * 512 + col]);
      w0x[g] = __builtin_bit_cast(bf16x8, t8);
    }
    #pragma unroll
    for (int kt = 0; kt < 8; ++kt) {
      short8_t t8;
      #pragma unroll
      for (int e = 0; e < 8; ++e) t8[e] = (short)f2bf(sc * W1[(kt * 32 + lh * 8 + e) * 512 + col]);
      w1f[g][kt] = __builtin_bit_cast(bf16x8, t8);
    }
    #pragma unroll
    for (int kt = 0; kt < 4; ++kt) {
      const int base = (((w * 4 + g) * 4) + kt) * 512 + l * 8;
      #pragma unroll
      for (int e = 0; e < 8; ++e)
        w0h[base + e] = f2bf(sc * W0[(32 + kt * 32 + lh * 8 + e) * 512 + col]);
    }
  }
  { // Wout B-frags with dts*DT folded in
    const int n = w & 1, kt = w >> 1;
    if (kt < 4) {
      const float csc = dts[n * 16 + lm] * 0.01f;
      const int base = (n * 4 + kt) * 512 + l * 8;
      #pragma unroll
      for (int e = 0; e < 8; ++e)
        woutF[base + e] = f2bf(csc * Wout[(kt * 32 + lh * 8 + e) * 32 + (n * 16 + lm)]);
    }
  }
  float b0r[4], b1r[4];
  #pragma unroll
  for (int g = 0; g < 4; ++g) {
    const float sc = (g == 2) ? TWO_LOG2E : LOG2E;
    b0r[g] = sc * b0v[g * 128 + w * 16 + lm];
    b1r[g] = sc * b1v[g * 128 + w * 16 + lm];
  }

  // proj/store mapping: waves 0,1 -> stream0 (n_c = w&1); waves 2,3 -> stream1
  const int S_w = (w >> 1) & 1;
  const int n_c = w & 1;
  float boutr = 0.f, xr[4] = {0.f, 0.f, 0.f, 0.f};
  long obase0 = 0;
  int  xfb = 0;
  if (w < 4) {
    boutr = bout[n_c * 16 + lm] * dts[n_c * 16 + lm] * 0.01f;
    const int kin = n_c * 16 + lm;
    xfb = (lh * 4 + 16 * (kin >> 3)) * 8 + (kin & 7);
    obase0 = (bbase + S_w * 16 + lh * 4) * rowStride + (n_c * 16 + lm);
    unsigned short* xfS = S_w ? xf1 : xf0;
    #pragma unroll
    for (int r = 0; r < 4; ++r) {
      xr[r] = x0[(bbase + S_w * 16 + lh * 4 + r) * 32 + n_c * 16 + lm];
      out[obase0 + r * rowStride] = xr[r];   // trajectory t = 0
      xfS[xfb + r * 8] = f2bf(xr[r]);        // seed xf(0)
    }
  }
  for (int i = tid; i < 4 * 512; i += 512) {
    h0f0[i] = 0; h0f1[i] = 0; h1f0[i] = 0; h1f1[i] = 0;
  }

  // h-write scatter base (per-stream fragment layout; kt = w>>1)
  const int hwb = (w >> 1) * 512 +
                  (lh * 4 + 16 * (2 * (w & 1) + ((lm >> 3) & 1))) * 8 + (lm & 7);

  // c-states live in the 2*log2e-scaled domain
  float4_t c0s0 = {0.f,0.f,0.f,0.f}, c0s1 = {0.f,0.f,0.f,0.f};
  float4_t c1s0 = {0.f,0.f,0.f,0.f}, c1s1 = {0.f,0.f,0.f,0.f};

#define INIT4(ACC, B) \
    _Pragma("unroll") \
    for (int g = 0; g < 4; ++g) (ACC)[g] = (float4_t){(B)[g], (B)[g], (B)[g], (B)[g]};

#define CELL0H(HSRC, ACC) \
    _Pragma("unroll") \
    for (int kt = 0; kt < 4; ++kt) { \
      const bf16x8 a = *(const bf16x8*)&(HSRC)[kt * 512 + l * 8]; \
      _Pragma("unroll") \
      for (int g = 0; g < 4; ++g) { \
        const bf16x8 bw = *(const bf16x8*)&w0h[(((w * 4 + g) * 4) + kt) * 512 + l * 8]; \
        (ACC)[g] = MFMA(a, bw, (ACC)[g]); \
      } \
    }

#define XPART(XSRC, ACC) { \
    const bf16x8 ax = *(const bf16x8*)&(XSRC)[l * 8]; \
    _Pragma("unroll") \
    for (int g = 0; g < 4; ++g) (ACC)[g] = MFMA(ax, w0x[g], (ACC)[g]); \
  }

#define CELL1A(H0SRC, AM) \
    _Pragma("unroll") \
    for (int kt = 0; kt < 4; ++kt) { \
      const bf16x8 a = *(const bf16x8*)&(H0SRC)[kt * 512 + l * 8]; \
      _Pragma("unroll") \
      for (int g = 0; g < 4; ++g) (AM)[g] = MFMA(a, w1f[g][kt], (AM)[g]); \
    }
#define CELL1B(H1SRC, AM) \
    _Pragma("unroll") \
    for (int kt = 0; kt < 4; ++kt) { \
      const bf16x8 a = *(const bf16x8*)&(H1SRC)[kt * 512 + l * 8]; \
      _Pragma("unroll") \
      for (int g = 0; g < 4; ++g) (AM)[g] = MFMA(a, w1f[g][kt + 4], (AM)[g]); \
    }

// LSTM elementwise in scaled-c domain: gates ACC (i,f,o pre-scaled by log2e,
// g by 2log2e), CS = 2log2e*c_true. Independent per-element chains (max ILP).
#define ACT4(ACC, CS, DST) \
    _Pragma("unroll") \
    for (int r = 0; r < 4; ++r) { \
      const float iv = sig2((ACC)[0][r]); \
      const float fv = sig2((ACC)[1][r]); \
      const float tg = __builtin_amdgcn_rcpf(1.f + __builtin_amdgcn_exp2f((ACC)[2][r])); \
      const float ov = sig2((ACC)[3][r]); \
      const float gs = TWO_LOG2E - 2.f * TWO_LOG2E * tg; \
      const float cc = fv * (CS)[r] + iv * gs; \
      (CS)[r] = cc; \
      const float tc = __builtin_amdgcn_rcpf(1.f + __builtin_amdgcn_exp2f(cc)); \
      const float hv = ov - 2.f * ov * tc; \
      DST; \
    }

#define PROJ(H1SRC, XFDST) { \
    float4_t dacc = (float4_t){boutr, boutr, boutr, boutr}; \
    _Pragma("unroll") \
    for (int kt = 0; kt < 4; ++kt) { \
      const bf16x8 a  = *(const bf16x8*)&(H1SRC)[kt * 512 + l * 8]; \
      const bf16x8 bw = *(const bf16x8*)&woutF[(n_c * 4 + kt) * 512 + l * 8]; \
      dacc = MFMA(a, bw, dacc); \
    } \
    _Pragma("unroll") \
    for (int r = 0; r < 4; ++r) { \
      xr[r] += dacc[r]; \
      (XFDST)[xfb + r * 8] = f2bf(xr[r]); \
    } \
  }

  float4_t am1[4];            // s1's cell1 gates, pending act (crosses iters)
  INIT4(am1, b1r);

  __syncthreads();   // publish packing, xf seeds, h zeros

  #pragma unroll 1
  for (int t = 0; t < T; ++t) {
    // ===== R1: cell0h(s0) ; act1(s1,t-1) -> h1f1 ; proj(s0) =====
    float4_t acc0s0[4];
    INIT4(acc0s0, b0r);
    CELL0H(h0f0, acc0s0);
    if (t > 0) {
      ACT4(am1, c1s1, h1f1[hwb + r * 8] = f2bf(hv));
      if (w < 2) PROJ(h1f0, xf0);
    }
    __syncthreads();

    // ===== R2: x-part+act0(s0) -> h0f0 ; cell0h(s1) ; proj(s1) =====
    float4_t acc0s1[4];
    XPART(xf0, acc0s0);
    INIT4(acc0s1, b0r);
    CELL0H(h0f1, acc0s1);
    ACT4(acc0s0, c0s0, h0f0[hwb + r * 8] = f2bf(hv));
    if (w >= 2 && w < 4 && t > 0) PROJ(h1f1, xf1);
    __syncthreads();

    // ===== R3: stores x0(t) ; cell1(s0) -> am0 ; x-part+act0(s1) -> h0f1 =====
    if (w < 2 && t > 0) {
      const long ob = obase0 + (long)t * 32;
      #pragma unroll
      for (int r = 0; r < 4; ++r) out[ob + r * rowStride] = xr[r];
    }
    float4_t am0[4];
    INIT4(am0, b1r);
    CELL1A(h0f0, am0);
    XPART(xf1, acc0s1);
    ACT4(acc0s1, c0s1, h0f1[hwb + r * 8] = f2bf(hv));
    CELL1B(h1f0, am0);
    __syncthreads();

    // ===== R4: stores x1(t) ; act1(s0) -> h1f0 ; cell1(s1) -> am1 =====
    if (w >= 2 && w < 4 && t > 0) {
      const long ob = obase0 + (long)t * 32;
      #pragma unroll
      for (int r = 0; r < 4; ++r) out[ob + r * rowStride] = xr[r];
    }
    ACT4(am0, c1s0, h1f0[hwb + r * 8] = f2bf(hv));
    INIT4(am1, b1r);
    CELL1A(h0f1, am1);
    CELL1B(h1f1, am1);
    __syncthreads();
  }

  // ===== Epilogue: act1(s1,T-1) -> h1f1, then final projections x(T) =====
  ACT4(am1, c1s1, h1f1[hwb + r * 8] = f2bf(hv));
  if (w < 2) {   // x0(T): h1f0 holds h1(T-1), published at last R4 barrier
    float4_t dacc = (float4_t){boutr, boutr, boutr, boutr};
    #pragma unroll
    for (int kt = 0; kt < 4; ++kt) {
      const bf16x8 a  = *(const bf16x8*)&h1f0[kt * 512 + l * 8];
      const bf16x8 bw = *(const bf16x8*)&woutF[(n_c * 4 + kt) * 512 + l * 8];
      dacc = MFMA(a, bw, dacc);
    }
    const long ob = obase0 + (long)T * 32;
    #pragma unroll
    for (int r = 0; r < 4; ++r) {
      xr[r] += dacc[r];
      out[ob + r * rowStride] = xr[r];
    }
  }
  __syncthreads();   // publish h1f1
  if (w >= 2 && w < 4) {   // x1(T)
    float4_t dacc = (float4_t){boutr, boutr, boutr, boutr};
    #pragma unroll
    for (int kt = 0; kt < 4; ++kt) {
      const bf16x8 a  = *(const bf16x8*)&h1f1[kt * 512 + l * 8];
      const bf16x8 bw = *(const bf16x8*)&woutF[(n_c * 4 + kt) * 512 + l * 8];
      dacc = MFMA(a, bw, dacc);
    }
    const long ob = obase0 + (long)T * 32;
    #pragma unroll
    for (int r = 0; r < 4; ++r) {
      xr[r] += dacc[r];
      out[ob + r * rowStride] = xr[r];
    }
  }
}

extern "C" void kernel_launch(void* const* d_in, const int* in_sizes, int n_in,
                              void* d_out, int out_size, void* d_ws, size_t ws_size,
                              hipStream_t stream) {
  (void)n_in; (void)out_size; (void)d_ws; (void)ws_size;
  const float* x0   = (const float*)d_in[0];
  const float* W0   = (const float*)d_in[1];
  const float* b0   = (const float*)d_in[2];
  const float* W1   = (const float*)d_in[3];
  const float* b1   = (const float*)d_in[4];
  const float* Wout = (const float*)d_in[5];
  const float* bout = (const float*)d_in[6];
  const float* dts  = (const float*)d_in[7];
  const int*   nsp  = (const int*)d_in[8];
  float* out = (float*)d_out;

  const int B    = in_sizes[0] / 32;   // 8192
  const int grid = B / 32;             // 256 blocks, 32 batch rows each
  lstm_roll<<<dim3(grid), dim3(512), 0, stream>>>(x0, W0, b0, W1, b1, Wout, bout, dts, nsp, out);
}